// Round 15
// baseline (332.870 us; speedup 1.0000x reference)
//
#include <hip/hip_runtime.h>
#include <hip/hip_bf16.h>

// SelectiveSSM: B=1, L=2048, D_MODEL=512, D_INNER=1024, D_STATE=16, D_CONV=4
// ESTABLISHED: inputs fp32, d_out fp32, ws >= 17.05MB. R14: 264us =
// scan 106 (latency-bound, VALU floor ~29us) + other 158 (11 launches,
// 64-tile GEMMs ~100TF). Scan WRITE counter (~128MB) proven insensitive to
// NT stores -> attribution artifact, dropped as a signal.
// R15: fuse pre-passes into GEMMs + 128x128 tile:
//   - gemm128: A fp32/bf16 cast-on-stage, B fp32 [K][N] transpose-cast-on-
//     stage (LDS BT layout), C bf16/fp32. Replaces cast+transpose_cast+64tile.
//   - gemm_xproj: B=W_xproj fp32 [1024][33] pad/transpose on stage, C stored
//     transposed straight to xpcT[33][2048]. Replaces wxproj_pad+xp_compact.
//   - 12 launches -> 8. Scan/conv/transpose/gate unchanged from R14.
// ws: buf0 4MB@0 | buf1 4MB@4 | xsT 4MB@8 | xpcT 270KB@12MB. (12.3MB)

#define L_SEQ 2048
#define DM 512
#define DI 1024
#define DS 16
#define NXP 33
#define EPS 1e-10f
#define LOG2E 1.44269504088896340736f
#define LN2 0.69314718055994530942f
#define LOG2EPS -33.219280948873623478f  // log2(1e-10)

typedef __hip_bfloat16 bf16;
typedef __attribute__((ext_vector_type(8))) short bf16x8v;
typedef __attribute__((ext_vector_type(4))) float f32x4v;
typedef __attribute__((ext_vector_type(4))) unsigned int u32x4v;

__device__ __forceinline__ float ldf(const float* p) { return *p; }
__device__ __forceinline__ float ldf(const bf16* p) { return __bfloat162float(*p); }

struct alignas(8) bf16x4 { bf16 x, y, z, w; };

__device__ __forceinline__ void st1(float* p, float v) { *p = v; }
__device__ __forceinline__ void st1(bf16* p, float v) { *p = __float2bfloat16(v); }

__device__ __forceinline__ float fexp2(float x) { return __builtin_amdgcn_exp2f(x); }
__device__ __forceinline__ float frcp(float x) { return __builtin_amdgcn_rcpf(x); }

// load 8 consecutive elements as fp32
__device__ __forceinline__ void load8(const float* p, float* v) {
  float4 a = *(const float4*)p;
  float4 b = *(const float4*)(p + 4);
  v[0] = a.x; v[1] = a.y; v[2] = a.z; v[3] = a.w;
  v[4] = b.x; v[5] = b.y; v[6] = b.z; v[7] = b.w;
}
__device__ __forceinline__ void load8(const bf16* p, float* v) {
  bf16 t[8];
  *(uint4*)t = *(const uint4*)p;
#pragma unroll
  for (int j = 0; j < 8; ++j) v[j] = __bfloat162float(t[j]);
}

// ---------- 128x128-tile MFMA GEMM ----------
// C[M][N] = A[M][K] @ B[K][N]. A: fp32 or bf16 (cast on stage). B: fp32
// row-major, transpose-cast during staging into LDS BT layout. 256 threads.
template <typename TA, typename TC>
__global__ __launch_bounds__(256)
void gemm128(const TA* __restrict__ A, const float* __restrict__ B,
             TC* __restrict__ C, int M, int N, int K,
             int lda, int ldb, int ldc) {
  __shared__ __align__(16) bf16 As[128 * 40];
  __shared__ __align__(16) bf16 Bs[128 * 40];
  const int tid = threadIdx.x;
  const int wave = tid >> 6, lane = tid & 63;
  const int q = lane >> 4, r = lane & 15;
  const int row0 = blockIdx.y * 128, col0 = blockIdx.x * 128;
  f32x4v acc[2][8] = {};
  for (int k0 = 0; k0 < K; k0 += 32) {
    // A: 128 rows x 32 k. thread: m = tid>>1, koff = (tid&1)*16.
    {
      int m = tid >> 1, koff = (tid & 1) * 16;
      const TA* ap = A + (size_t)(row0 + m) * lda + k0 + koff;
      float v[16];
      load8(ap, v);
      load8(ap + 8, v + 8);
      bf16* dst = &As[m * 40 + koff];
#pragma unroll
      for (int j = 0; j < 16; ++j) dst[j] = __float2bfloat16(v[j]);
    }
    // B: 32 k-rows x 128 n, transposed into Bs[n][k]. thread: k=tid>>3,
    // n0=(tid&7)*16.
    {
      int k = tid >> 3, n0 = (tid & 7) * 16;
      const float* bp = B + (size_t)(k0 + k) * ldb + col0 + n0;
      float v[16];
      load8(bp, v);
      load8(bp + 8, v + 8);
#pragma unroll
      for (int j = 0; j < 16; ++j) Bs[(n0 + j) * 40 + k] = __float2bfloat16(v[j]);
    }
    __syncthreads();
#pragma unroll
    for (int sub = 0; sub < 2; ++sub) {
      bf16x8v a = *(const bf16x8v*)&As[(wave * 32 + sub * 16 + r) * 40 + q * 8];
#pragma unroll
      for (int j = 0; j < 8; ++j) {
        bf16x8v b = *(const bf16x8v*)&Bs[(j * 16 + r) * 40 + q * 8];
        acc[sub][j] = __builtin_amdgcn_mfma_f32_16x16x32_bf16(a, b, acc[sub][j], 0, 0, 0);
      }
    }
    __syncthreads();
  }
#pragma unroll
  for (int sub = 0; sub < 2; ++sub)
#pragma unroll
    for (int j = 0; j < 8; ++j)
#pragma unroll
      for (int reg = 0; reg < 4; ++reg) {
        int m = row0 + wave * 32 + sub * 16 + q * 4 + reg;
        int n = col0 + j * 16 + r;
        st1(C + (size_t)m * ldc + n, acc[sub][j][reg]);
      }
}

// ---------- xproj GEMM: xpcT[j][l] = (xs @ W_xproj)[l][j], 64-tile ----------
// A = xs bf16 [2048][1024]; B = W_xproj fp32 [1024][33] (pad n>=33 with 0,
// transpose-cast on stage); C stored transposed directly into xpcT[33][2048].
__global__ __launch_bounds__(256)
void gemm_xproj(const bf16* __restrict__ A, const float* __restrict__ Wx,
                float* __restrict__ xpcT) {
  __shared__ __align__(16) bf16 As[64 * 40];
  __shared__ __align__(16) bf16 Bs[64 * 40];
  const int tid = threadIdx.x;
  const int wave = tid >> 6, lane = tid & 63;
  const int q = lane >> 4, r = lane & 15;
  const int row0 = blockIdx.y * 64;
  const int srow = tid >> 2, sseg = tid & 3;
  f32x4v acc[4] = {};
  for (int k0 = 0; k0 < DI; k0 += 32) {
    uint4 av = *(const uint4*)(A + (size_t)(row0 + srow) * DI + k0 + sseg * 8);
    *(uint4*)&As[srow * 40 + sseg * 8] = av;
    int k = tid >> 3, n0 = (tid & 7) * 8;
#pragma unroll
    for (int j = 0; j < 8; ++j) {
      int n = n0 + j;
      float v = (n < NXP) ? Wx[(size_t)(k0 + k) * NXP + n] : 0.f;
      Bs[n * 40 + k] = __float2bfloat16(v);
    }
    __syncthreads();
    bf16x8v a = *(const bf16x8v*)&As[(wave * 16 + r) * 40 + q * 8];
#pragma unroll
    for (int j = 0; j < 4; ++j) {
      bf16x8v b = *(const bf16x8v*)&Bs[(j * 16 + r) * 40 + q * 8];
      acc[j] = __builtin_amdgcn_mfma_f32_16x16x32_bf16(a, b, acc[j], 0, 0, 0);
    }
    __syncthreads();
  }
#pragma unroll
  for (int j = 0; j < 4; ++j)
#pragma unroll
    for (int reg = 0; reg < 4; ++reg) {
      int m = row0 + wave * 16 + q * 4 + reg;
      int n = j * 16 + r;
      if (n < NXP) xpcT[(size_t)n * L_SEQ + m] = acc[j][reg];
    }
}

// ---------- glue kernels (unchanged from R14) ----------

// bf16 [R][C] -> [C][R], 64x64 tiles.
__global__ __launch_bounds__(256)
void transpose_bf16(const bf16* __restrict__ in, bf16* __restrict__ out,
                    int R, int C) {
  __shared__ bf16 tile[64][72];
  int r0 = blockIdx.y * 64, c0 = blockIdx.x * 64;
#pragma unroll
  for (int it = 0; it < 2; ++it) {
    int slot = threadIdx.x + it * 256;
    int rr = slot >> 3, seg = slot & 7;
    *(uint4*)&tile[rr][seg * 8] = *(const uint4*)(in + (size_t)(r0 + rr) * C + c0 + seg * 8);
  }
  __syncthreads();
#pragma unroll
  for (int it = 0; it < 2; ++it) {
    int slot = threadIdx.x + it * 256;
    int cc = slot >> 3, seg = slot & 7;
    bf16 tmp[8];
#pragma unroll
    for (int j = 0; j < 8; ++j) tmp[j] = tile[seg * 8 + j][cc];
    *(uint4*)(out + (size_t)(c0 + cc) * R + r0 + seg * 8) = *(uint4*)tmp;
  }
}

// ys[l][d] = yT[d][l] * silu(z[l][d]).
__global__ __launch_bounds__(256)
void gate_transpose_kernel(const bf16* __restrict__ yT, const bf16* __restrict__ zbuf,
                           bf16* __restrict__ ys) {
  __shared__ bf16 tile[64][72];
  int d0 = blockIdx.y * 64, l0 = blockIdx.x * 64;
#pragma unroll
  for (int it = 0; it < 2; ++it) {
    int slot = threadIdx.x + it * 256;
    int dd = slot >> 3, seg = slot & 7;
    *(uint4*)&tile[dd][seg * 8] = *(const uint4*)(yT + (size_t)(d0 + dd) * L_SEQ + l0 + seg * 8);
  }
  __syncthreads();
#pragma unroll
  for (int it = 0; it < 2; ++it) {
    int slot = threadIdx.x + it * 256;
    int ll = slot >> 3, seg = slot & 7;
    bf16 zt[8];
    *(uint4*)zt = *(const uint4*)(zbuf + (size_t)(l0 + ll) * DI + d0 + seg * 8);
    bf16 o[8];
#pragma unroll
    for (int j = 0; j < 8; ++j) {
      float yv = __bfloat162float(tile[seg * 8 + j][ll]);
      float zv = __bfloat162float(zt[j]);
      o[j] = __float2bfloat16(yv * zv * frcp(1.f + fexp2(-zv * LOG2E)));
    }
    *(uint4*)(ys + (size_t)(l0 + ll) * DI + d0 + seg * 8) = *(uint4*)o;
  }
}

// Depthwise causal conv (width 4) + bias + SiLU.
template <typename T>
__global__ __launch_bounds__(256)
void conv_silu_kernel(const T* __restrict__ xpre, const float* __restrict__ conv_w,
                      const float* __restrict__ conv_b, T* __restrict__ xs) {
  int idx = blockIdx.x * 256 + threadIdx.x;  // l*1024 + d
  int d = idx & (DI - 1);
  int l = idx >> 10;
  float acc = conv_b[d];
#pragma unroll
  for (int k = 0; k < 4; ++k) {
    int ls = l + k - 3;
    if (ls >= 0) acc = fmaf(ldf(xpre + (size_t)ls * DI + d), conv_w[d * 4 + k], acc);
  }
  st1(xs + idx, acc / (1.f + __expf(-acc)));
}

// ---------- chunk-parallel scan (unchanged from R14) ----------
#define LC 512
#define NW 16
#define SPW 32
#define PSX 513
#define LCP 516

__global__ __launch_bounds__(1024)
void scan_kernel(bf16* __restrict__ xsT, const float* __restrict__ xpcT,
                 const float* __restrict__ dt_w, const float* __restrict__ dt_b,
                 const float* __restrict__ A_log, const float* __restrict__ Dvec) {
  __shared__ float sxpT[NXP * PSX];
  __shared__ float sdt[4 * LCP], sg[4 * LCP], sxs[4 * LCP];
  __shared__ float sys[4 * LCP];
  __shared__ float Wtot[NW][64], Vtot[NW][64];
  const int tid = threadIdx.x;
  const int wave = tid >> 6, lane = tid & 63;
  const int s = lane & 15, dl = lane >> 4;
  const int d0 = blockIdx.x * 4;
  const int base = wave * SPW;
  const float As2 = -expf(A_log[s]) * LOG2E;
  const float Dd = Dvec[d0 + dl];
  float dtw[4], dtb[4];
#pragma unroll
  for (int c = 0; c < 4; ++c) {
    dtw[c] = dt_w[d0 + c];
    dtb[c] = dt_b[d0 + c];
  }
  float cs2_carry = 0.f, S_carry = 0.f;
  for (int l0 = 0; l0 < L_SEQ; l0 += LC) {
    for (int idx = tid; idx < NXP * LC; idx += 1024) {
      int j = idx >> 9, l = idx & (LC - 1);
      sxpT[j * PSX + l] = xpcT[(size_t)j * L_SEQ + l0 + l];
    }
    for (int slot = tid; slot < 4 * (LC / 8); slot += 1024) {
      int c = slot >> 6, seg = slot & 63;
      bf16 tmp[8];
      *(uint4*)tmp = *(const uint4*)(xsT + (size_t)(d0 + c) * L_SEQ + l0 + seg * 8);
#pragma unroll
      for (int j = 0; j < 8; ++j) sxs[c * LCP + seg * 8 + j] = __bfloat162float(tmp[j]);
    }
    __syncthreads();
    for (int i = tid; i < LC; i += 1024) {
      float x0 = sxpT[i];
#pragma unroll
      for (int c = 0; c < 4; ++c) {
        float a = fmaf(x0, dtw[c], dtb[c]);
        float dt = __log2f(1.f + fexp2(a * LOG2E)) * LN2;
        sdt[c * LCP + i] = dt;
        sg[c * LCP + i] = dt * sxs[c * LCP + i];
      }
    }
    __syncthreads();
    float u2[SPW];
    float Wl = 0.f;
#pragma unroll
    for (int k = 0; k < SPW; ++k) {
      u2[k] = sdt[dl * LCP + base + k] * As2;
      Wl += fmaxf(u2[k], LOG2EPS);
    }
    Wtot[wave][lane] = Wl;
    __syncthreads();
    float O = cs2_carry, Wall = 0.f;
    for (int w = 0; w < NW; ++w) {
      float t = Wtot[w][lane];
      if (w < wave) O += t;
      Wall += t;
    }
    float cs2 = O;
    float rcpA = frcp(fmaxf(fexp2(cs2), EPS));
    float Vl = 0.f;
#pragma unroll
    for (int k = 0; k < SPW; ++k) {
      float gb = sg[dl * LCP + base + k] * sxpT[(1 + s) * PSX + base + k];
      Vl = fmaf(gb, rcpA, Vl);
      cs2 += fmaxf(u2[k], LOG2EPS);
      rcpA = frcp(fmaxf(fexp2(cs2), EPS));
    }
    Vtot[wave][lane] = Vl;
    __syncthreads();
    float SO = S_carry, Vall = 0.f;
    for (int w = 0; w < NW; ++w) {
      float t = Vtot[w][lane];
      if (w < wave) SO += t;
      Vall += t;
    }
    cs2 = O;
    float S = SO;
    float acum_prev = fexp2(cs2);
#pragma unroll
    for (int k = 0; k < SPW; ++k) {
      float gb = sg[dl * LCP + base + k] * sxpT[(1 + s) * PSX + base + k];
      S = fmaf(gb, frcp(fmaxf(acum_prev, EPS)), S);
      cs2 += fmaxf(u2[k], LOG2EPS);
      float acum = fexp2(cs2);
      float h = acum * S * frcp(fmaxf(fexp2(u2[k]), EPS));
      float contrib = sxpT[(17 + s) * PSX + base + k] * h;
      acum_prev = acum;
      contrib += __shfl_xor(contrib, 8);
      contrib += __shfl_xor(contrib, 4);
      contrib += __shfl_xor(contrib, 2);
      contrib += __shfl_xor(contrib, 1);
      if (s == 0)
        sys[dl * LCP + base + k] = contrib + Dd * sxs[dl * LCP + base + k];
    }
    cs2_carry += Wall;
    S_carry += Vall;
    __syncthreads();
    for (int slot = tid; slot < 4 * (LC / 8); slot += 1024) {
      int c = slot >> 6, seg = slot & 63;
      bf16 tmp[8];
#pragma unroll
      for (int j = 0; j < 8; ++j) tmp[j] = __float2bfloat16(sys[c * LCP + seg * 8 + j]);
      u32x4v vv;
      vv.x = ((unsigned int*)tmp)[0]; vv.y = ((unsigned int*)tmp)[1];
      vv.z = ((unsigned int*)tmp)[2]; vv.w = ((unsigned int*)tmp)[3];
      __builtin_nontemporal_store(vv,
          (u32x4v*)(xsT + (size_t)(d0 + c) * L_SEQ + l0 + seg * 8));
    }
    __syncthreads();
  }
}

extern "C" void kernel_launch(void* const* d_in, const int* in_sizes, int n_in,
                              void* d_out, int out_size, void* d_ws, size_t ws_size,
                              hipStream_t stream) {
  const float* x       = (const float*)d_in[0];
  const float* W_in    = (const float*)d_in[1];
  const float* conv_w  = (const float*)d_in[2];
  const float* conv_b  = (const float*)d_in[3];
  const float* W_xproj = (const float*)d_in[4];
  const float* dt_w    = (const float*)d_in[5];
  const float* dt_b    = (const float*)d_in[6];
  const float* A_log   = (const float*)d_in[7];
  const float* Dvec    = (const float*)d_in[8];
  const float* W_out   = (const float*)d_in[9];
  float* out = (float*)d_out;

  char* ws = (char*)d_ws;
  const size_t MB = 1024 * 1024;
  bf16* buf0  = (bf16*)(ws);            // [2048][1024] xz x-half, then z
  bf16* buf1  = (bf16*)(ws + 4 * MB);   // [2048][1024] xs, later gated ys
  bf16* xsT   = (bf16*)(ws + 8 * MB);   // [1024][2048] xs^T, then y^T
  float* xpcT = (float*)(ws + 12 * MB); // [33][2048]

  // 1a) buf0 = x @ W_in[:, 0:1024]  (fp32 A/B staged+cast in-kernel)
  gemm128<float, bf16><<<dim3(DI / 128, L_SEQ / 128), 256, 0, stream>>>(
      x, W_in, buf0, L_SEQ, DI, DM, DM, 2 * DI, DI);
  // 2) conv + silu -> buf1 (xs, [l][d])
  conv_silu_kernel<bf16><<<L_SEQ * DI / 256, 256, 0, stream>>>(buf0, conv_w, conv_b, buf1);
  // 3) xpcT = (xs @ W_xproj)^T  (pad/transpose B on stage, C^T store)
  gemm_xproj<<<dim3(1, L_SEQ / 64), 256, 0, stream>>>(buf1, W_xproj, xpcT);
  // 1b) buf0 = x @ W_in[:, 1024:2048]  (z; x-pre dead)
  gemm128<float, bf16><<<dim3(DI / 128, L_SEQ / 128), 256, 0, stream>>>(
      x, W_in + DI, buf0, L_SEQ, DI, DM, DM, 2 * DI, DI);
  // 4) xs -> xsT
  transpose_bf16<<<dim3(DI / 64, L_SEQ / 64), 256, 0, stream>>>(buf1, xsT, L_SEQ, DI);
  // 5) scan: un-gated yT in place over xsT
  scan_kernel<<<DI / 4, 1024, 0, stream>>>(xsT, xpcT, dt_w, dt_b, A_log, Dvec);
  // 6) gate + transpose: ys[l][d] = yT * silu(z) -> buf1
  gate_transpose_kernel<<<dim3(L_SEQ / 64, DI / 64), 256, 0, stream>>>(xsT, buf0, buf1);
  // 7) out = ys @ W_out  (bf16 A, fp32 B staged in-kernel, fp32 C)
  gemm128<bf16, float><<<dim3(DM / 128, L_SEQ / 128), 256, 0, stream>>>(
      buf1, W_out, out, L_SEQ, DM, DI, DI, DM, DM);
}

// Round 16
// 262.770 us; speedup vs baseline: 1.2668x; 1.2668x over previous
//
#include <hip/hip_runtime.h>
#include <hip/hip_bf16.h>

// SelectiveSSM: B=1, L=2048, D_MODEL=512, D_INNER=1024, D_STATE=16, D_CONV=4
// ESTABLISHED: inputs fp32, d_out fp32, ws >= 17.05MB (R6 fp32 path ran).
// R15 regressed (333us): gemm128's B transpose-cast scatter = 16-way LDS bank
// conflict (bank = 20j + k>>1, n0 term vanishes mod 32) + 128/64-block grids
// idling 50-75% of CUs. R16 reverts to R14's 64-tile GEMM (512+ block grids,
// conflict-free staging) and consolidates launches 12 -> 9:
//  - single GEMM1 (N=2048, A=fp32 x cast-on-stage: contiguous, no scatter)
//  - conv fused with transpose (writes buf1[l][d] AND xsT[d][l])
//  - gemm_xproj (R15-proven) replaces wxpad+compact
//  - WoutT tcast runs late into the dead xsT slot
// ws 16.27MB: xz 8MB@0 | buf1 4MB@8 | shared 4MB@12 (WinT 2MB -> xsT 4MB ->
// WoutT 1MB) | xpcT 270KB@16MB.

#define L_SEQ 2048
#define DM 512
#define DI 1024
#define DS 16
#define NXP 33
#define EPS 1e-10f
#define LOG2E 1.44269504088896340736f
#define LN2 0.69314718055994530942f
#define LOG2EPS -33.219280948873623478f  // log2(1e-10)

typedef __hip_bfloat16 bf16;
typedef __attribute__((ext_vector_type(8))) short bf16x8v;
typedef __attribute__((ext_vector_type(4))) float f32x4v;
typedef __attribute__((ext_vector_type(4))) unsigned int u32x4v;

__device__ __forceinline__ float ldf(const float* p) { return *p; }
__device__ __forceinline__ float ldf(const bf16* p) { return __bfloat162float(*p); }

__device__ __forceinline__ void st1(float* p, float v) { *p = v; }
__device__ __forceinline__ void st1(bf16* p, float v) { *p = __float2bfloat16(v); }

__device__ __forceinline__ float fexp2(float x) { return __builtin_amdgcn_exp2f(x); }
__device__ __forceinline__ float frcp(float x) { return __builtin_amdgcn_rcpf(x); }

__device__ __forceinline__ void load8(const float* p, float* v) {
  float4 a = *(const float4*)p;
  float4 b = *(const float4*)(p + 4);
  v[0] = a.x; v[1] = a.y; v[2] = a.z; v[3] = a.w;
  v[4] = b.x; v[5] = b.y; v[6] = b.z; v[7] = b.w;
}
__device__ __forceinline__ void load8(const bf16* p, float* v) {
  bf16 t[8];
  *(uint4*)t = *(const uint4*)p;
#pragma unroll
  for (int j = 0; j < 8; ++j) v[j] = __bfloat162float(t[j]);
}

// W[R][C] fp32 -> WT[C][R] bf16, 32x32 LDS tiles. grid (C/32, R/32), 256 thr.
__global__ __launch_bounds__(256)
void transpose_cast_kernel(const float* __restrict__ W, bf16* __restrict__ WT,
                           int R, int C) {
  __shared__ float tile[32][33];
  int c0 = blockIdx.x * 32, r0 = blockIdx.y * 32;
  int tx = threadIdx.x & 31, ty = threadIdx.x >> 5;
#pragma unroll
  for (int i = 0; i < 4; ++i) {
    int rr = ty + i * 8;
    tile[rr][tx] = W[(size_t)(r0 + rr) * C + c0 + tx];
  }
  __syncthreads();
#pragma unroll
  for (int i = 0; i < 4; ++i) {
    int cc = ty + i * 8;
    WT[(size_t)(c0 + cc) * R + r0 + tx] = __float2bfloat16(tile[tx][cc]);
  }
}

// ---------- 64-tile MFMA GEMM: C[M][N] = A[M][K] @ BT[N][K]^T ----------
// A: fp32 (cast-on-stage, contiguous) or bf16. BT: bf16 rows of length K.
template <typename TA, typename TC>
__global__ __launch_bounds__(256)
void gemm_bt64(const TA* __restrict__ A, const bf16* __restrict__ BT,
               TC* __restrict__ C, int M, int N, int K, int lda, int ldc) {
  __shared__ __align__(16) bf16 As[64 * 40];
  __shared__ __align__(16) bf16 Bs[64 * 40];
  const int tid = threadIdx.x;
  const int wave = tid >> 6, lane = tid & 63;
  const int q = lane >> 4, r = lane & 15;
  const int row0 = blockIdx.y * 64, col0 = blockIdx.x * 64;
  const int srow = tid >> 2, sseg = tid & 3;
  f32x4v acc[4] = {};
  for (int k0 = 0; k0 < K; k0 += 32) {
    {
      float v[8];
      load8(A + (size_t)(row0 + srow) * lda + k0 + sseg * 8, v);
      bf16* dst = &As[srow * 40 + sseg * 8];
#pragma unroll
      for (int j = 0; j < 8; ++j) dst[j] = __float2bfloat16(v[j]);
    }
    *(uint4*)&Bs[srow * 40 + sseg * 8] =
        *(const uint4*)(BT + (size_t)(col0 + srow) * K + k0 + sseg * 8);
    __syncthreads();
    bf16x8v a = *(const bf16x8v*)&As[(wave * 16 + r) * 40 + q * 8];
#pragma unroll
    for (int j = 0; j < 4; ++j) {
      bf16x8v b = *(const bf16x8v*)&Bs[(j * 16 + r) * 40 + q * 8];
      acc[j] = __builtin_amdgcn_mfma_f32_16x16x32_bf16(a, b, acc[j], 0, 0, 0);
    }
    __syncthreads();
  }
#pragma unroll
  for (int j = 0; j < 4; ++j)
#pragma unroll
    for (int reg = 0; reg < 4; ++reg) {
      int m = row0 + wave * 16 + q * 4 + reg;
      int n = col0 + j * 16 + r;
      st1(C + (size_t)m * ldc + n, acc[j][reg]);
    }
}

// bf16 staging variant of A (direct uint4 copy, no cvt)
template <>
__global__ __launch_bounds__(256)
void gemm_bt64<bf16, float>(const bf16* __restrict__ A, const bf16* __restrict__ BT,
                            float* __restrict__ C, int M, int N, int K,
                            int lda, int ldc) {
  __shared__ __align__(16) bf16 As[64 * 40];
  __shared__ __align__(16) bf16 Bs[64 * 40];
  const int tid = threadIdx.x;
  const int wave = tid >> 6, lane = tid & 63;
  const int q = lane >> 4, r = lane & 15;
  const int row0 = blockIdx.y * 64, col0 = blockIdx.x * 64;
  const int srow = tid >> 2, sseg = tid & 3;
  f32x4v acc[4] = {};
  for (int k0 = 0; k0 < K; k0 += 32) {
    *(uint4*)&As[srow * 40 + sseg * 8] =
        *(const uint4*)(A + (size_t)(row0 + srow) * lda + k0 + sseg * 8);
    *(uint4*)&Bs[srow * 40 + sseg * 8] =
        *(const uint4*)(BT + (size_t)(col0 + srow) * K + k0 + sseg * 8);
    __syncthreads();
    bf16x8v a = *(const bf16x8v*)&As[(wave * 16 + r) * 40 + q * 8];
#pragma unroll
    for (int j = 0; j < 4; ++j) {
      bf16x8v b = *(const bf16x8v*)&Bs[(j * 16 + r) * 40 + q * 8];
      acc[j] = __builtin_amdgcn_mfma_f32_16x16x32_bf16(a, b, acc[j], 0, 0, 0);
    }
    __syncthreads();
  }
#pragma unroll
  for (int j = 0; j < 4; ++j)
#pragma unroll
    for (int reg = 0; reg < 4; ++reg) {
      int m = row0 + wave * 16 + q * 4 + reg;
      int n = col0 + j * 16 + r;
      st1(C + (size_t)m * ldc + n, acc[j][reg]);
    }
}

// ---------- xproj GEMM (R15-proven): xpcT[j][l] = (xs @ W_xproj)[l][j] ----
__global__ __launch_bounds__(256)
void gemm_xproj(const bf16* __restrict__ A, const float* __restrict__ Wx,
                float* __restrict__ xpcT) {
  __shared__ __align__(16) bf16 As[64 * 40];
  __shared__ __align__(16) bf16 Bs[64 * 40];
  const int tid = threadIdx.x;
  const int wave = tid >> 6, lane = tid & 63;
  const int q = lane >> 4, r = lane & 15;
  const int row0 = blockIdx.y * 64;
  const int srow = tid >> 2, sseg = tid & 3;
  f32x4v acc[4] = {};
  for (int k0 = 0; k0 < DI; k0 += 32) {
    *(uint4*)&As[srow * 40 + sseg * 8] =
        *(const uint4*)(A + (size_t)(row0 + srow) * DI + k0 + sseg * 8);
    int k = tid >> 3, n0 = (tid & 7) * 8;
#pragma unroll
    for (int j = 0; j < 8; ++j) {
      int n = n0 + j;
      float v = (n < NXP) ? Wx[(size_t)(k0 + k) * NXP + n] : 0.f;
      Bs[n * 40 + k] = __float2bfloat16(v);
    }
    __syncthreads();
    bf16x8v a = *(const bf16x8v*)&As[(wave * 16 + r) * 40 + q * 8];
#pragma unroll
    for (int j = 0; j < 4; ++j) {
      bf16x8v b = *(const bf16x8v*)&Bs[(j * 16 + r) * 40 + q * 8];
      acc[j] = __builtin_amdgcn_mfma_f32_16x16x32_bf16(a, b, acc[j], 0, 0, 0);
    }
    __syncthreads();
  }
#pragma unroll
  for (int j = 0; j < 4; ++j)
#pragma unroll
    for (int reg = 0; reg < 4; ++reg) {
      int m = row0 + wave * 16 + q * 4 + reg;
      int n = j * 16 + r;
      if (n < NXP) xpcT[(size_t)n * L_SEQ + m] = acc[j][reg];
    }
}

// ---------- conv + silu, dual-layout output ----------
// Reads xz x-half (ld 2048), writes xs to buf1[l][d] and xsT[d][l].
// grid (DI/64, L/64), 256 threads. Causal width-4 conv along l.
__global__ __launch_bounds__(256)
void conv_silu_dual(const bf16* __restrict__ xz, const float* __restrict__ conv_w,
                    const float* __restrict__ conv_b, bf16* __restrict__ xs,
                    bf16* __restrict__ xsT) {
  __shared__ bf16 tile[67][72];   // rows l0-3 .. l0+63
  __shared__ bf16 sout[64][72];   // [d][l]
  const int tid = threadIdx.x;
  const int d0 = blockIdx.x * 64, l0 = blockIdx.y * 64;
  // stage 67 rows x 64 cols
  for (int slot = tid; slot < 67 * 8; slot += 256) {
    int rr = slot >> 3, seg = slot & 7;
    int l = l0 - 3 + rr;
    uint4 v = {0, 0, 0, 0};
    if (l >= 0) v = *(const uint4*)(xz + (size_t)l * (2 * DI) + d0 + seg * 8);
    *(uint4*)&tile[rr][seg * 8] = v;
  }
  __syncthreads();
  // compute: thread -> 2 rows x 8 cols
  {
    int lr = tid >> 3, c0t = (tid & 7) * 8;
#pragma unroll
    for (int half = 0; half < 2; ++half) {
      int lrow = lr + half * 32;
      bf16 o[8];
#pragma unroll
      for (int j = 0; j < 8; ++j) {
        int c = c0t + j;
        float acc = conv_b[d0 + c];
#pragma unroll
        for (int k = 0; k < 4; ++k)
          acc = fmaf(__bfloat162float(tile[lrow + k][c]), conv_w[(d0 + c) * 4 + k], acc);
        float v = acc / (1.f + __expf(-acc));
        o[j] = __float2bfloat16(v);
        sout[c][lrow] = o[j];
      }
      *(uint4*)(xs + (size_t)(l0 + lrow) * DI + d0 + c0t) = *(uint4*)o;
    }
  }
  __syncthreads();
  for (int slot = tid; slot < 64 * 8; slot += 256) {
    int dd = slot >> 3, seg = slot & 7;
    *(uint4*)(xsT + (size_t)(d0 + dd) * L_SEQ + l0 + seg * 8) =
        *(uint4*)&sout[dd][seg * 8];
  }
}

// ys[l][d] = yT[d][l] * silu(z[l][d]); z has leading dim ldz.
__global__ __launch_bounds__(256)
void gate_transpose_kernel(const bf16* __restrict__ yT, const bf16* __restrict__ zbuf,
                           int ldz, bf16* __restrict__ ys) {
  __shared__ bf16 tile[64][72];
  int d0 = blockIdx.y * 64, l0 = blockIdx.x * 64;
#pragma unroll
  for (int it = 0; it < 2; ++it) {
    int slot = threadIdx.x + it * 256;
    int dd = slot >> 3, seg = slot & 7;
    *(uint4*)&tile[dd][seg * 8] = *(const uint4*)(yT + (size_t)(d0 + dd) * L_SEQ + l0 + seg * 8);
  }
  __syncthreads();
#pragma unroll
  for (int it = 0; it < 2; ++it) {
    int slot = threadIdx.x + it * 256;
    int ll = slot >> 3, seg = slot & 7;
    bf16 zt[8];
    *(uint4*)zt = *(const uint4*)(zbuf + (size_t)(l0 + ll) * ldz + d0 + seg * 8);
    bf16 o[8];
#pragma unroll
    for (int j = 0; j < 8; ++j) {
      float yv = __bfloat162float(tile[seg * 8 + j][ll]);
      float zv = __bfloat162float(zt[j]);
      o[j] = __float2bfloat16(yv * zv * frcp(1.f + fexp2(-zv * LOG2E)));
    }
    *(uint4*)(ys + (size_t)(l0 + ll) * DI + d0 + seg * 8) = *(uint4*)o;
  }
}

// ---------- chunk-parallel scan (unchanged from R14) ----------
#define LC 512
#define NW 16
#define SPW 32
#define PSX 513
#define LCP 516

__global__ __launch_bounds__(1024)
void scan_kernel(bf16* __restrict__ xsT, const float* __restrict__ xpcT,
                 const float* __restrict__ dt_w, const float* __restrict__ dt_b,
                 const float* __restrict__ A_log, const float* __restrict__ Dvec) {
  __shared__ float sxpT[NXP * PSX];
  __shared__ float sdt[4 * LCP], sg[4 * LCP], sxs[4 * LCP];
  __shared__ float sys[4 * LCP];
  __shared__ float Wtot[NW][64], Vtot[NW][64];
  const int tid = threadIdx.x;
  const int wave = tid >> 6, lane = tid & 63;
  const int s = lane & 15, dl = lane >> 4;
  const int d0 = blockIdx.x * 4;
  const int base = wave * SPW;
  const float As2 = -expf(A_log[s]) * LOG2E;
  const float Dd = Dvec[d0 + dl];
  float dtw[4], dtb[4];
#pragma unroll
  for (int c = 0; c < 4; ++c) {
    dtw[c] = dt_w[d0 + c];
    dtb[c] = dt_b[d0 + c];
  }
  float cs2_carry = 0.f, S_carry = 0.f;
  for (int l0 = 0; l0 < L_SEQ; l0 += LC) {
    for (int idx = tid; idx < NXP * LC; idx += 1024) {
      int j = idx >> 9, l = idx & (LC - 1);
      sxpT[j * PSX + l] = xpcT[(size_t)j * L_SEQ + l0 + l];
    }
    for (int slot = tid; slot < 4 * (LC / 8); slot += 1024) {
      int c = slot >> 6, seg = slot & 63;
      bf16 tmp[8];
      *(uint4*)tmp = *(const uint4*)(xsT + (size_t)(d0 + c) * L_SEQ + l0 + seg * 8);
#pragma unroll
      for (int j = 0; j < 8; ++j) sxs[c * LCP + seg * 8 + j] = __bfloat162float(tmp[j]);
    }
    __syncthreads();
    for (int i = tid; i < LC; i += 1024) {
      float x0 = sxpT[i];
#pragma unroll
      for (int c = 0; c < 4; ++c) {
        float a = fmaf(x0, dtw[c], dtb[c]);
        float dt = __log2f(1.f + fexp2(a * LOG2E)) * LN2;
        sdt[c * LCP + i] = dt;
        sg[c * LCP + i] = dt * sxs[c * LCP + i];
      }
    }
    __syncthreads();
    float u2[SPW];
    float Wl = 0.f;
#pragma unroll
    for (int k = 0; k < SPW; ++k) {
      u2[k] = sdt[dl * LCP + base + k] * As2;
      Wl += fmaxf(u2[k], LOG2EPS);
    }
    Wtot[wave][lane] = Wl;
    __syncthreads();
    float O = cs2_carry, Wall = 0.f;
    for (int w = 0; w < NW; ++w) {
      float t = Wtot[w][lane];
      if (w < wave) O += t;
      Wall += t;
    }
    float cs2 = O;
    float rcpA = frcp(fmaxf(fexp2(cs2), EPS));
    float Vl = 0.f;
#pragma unroll
    for (int k = 0; k < SPW; ++k) {
      float gb = sg[dl * LCP + base + k] * sxpT[(1 + s) * PSX + base + k];
      Vl = fmaf(gb, rcpA, Vl);
      cs2 += fmaxf(u2[k], LOG2EPS);
      rcpA = frcp(fmaxf(fexp2(cs2), EPS));
    }
    Vtot[wave][lane] = Vl;
    __syncthreads();
    float SO = S_carry, Vall = 0.f;
    for (int w = 0; w < NW; ++w) {
      float t = Vtot[w][lane];
      if (w < wave) SO += t;
      Vall += t;
    }
    cs2 = O;
    float S = SO;
    float acum_prev = fexp2(cs2);
#pragma unroll
    for (int k = 0; k < SPW; ++k) {
      float gb = sg[dl * LCP + base + k] * sxpT[(1 + s) * PSX + base + k];
      S = fmaf(gb, frcp(fmaxf(acum_prev, EPS)), S);
      cs2 += fmaxf(u2[k], LOG2EPS);
      float acum = fexp2(cs2);
      float h = acum * S * frcp(fmaxf(fexp2(u2[k]), EPS));
      float contrib = sxpT[(17 + s) * PSX + base + k] * h;
      acum_prev = acum;
      contrib += __shfl_xor(contrib, 8);
      contrib += __shfl_xor(contrib, 4);
      contrib += __shfl_xor(contrib, 2);
      contrib += __shfl_xor(contrib, 1);
      if (s == 0)
        sys[dl * LCP + base + k] = contrib + Dd * sxs[dl * LCP + base + k];
    }
    cs2_carry += Wall;
    S_carry += Vall;
    __syncthreads();
    for (int slot = tid; slot < 4 * (LC / 8); slot += 1024) {
      int c = slot >> 6, seg = slot & 63;
      bf16 tmp[8];
#pragma unroll
      for (int j = 0; j < 8; ++j) tmp[j] = __float2bfloat16(sys[c * LCP + seg * 8 + j]);
      u32x4v vv;
      vv.x = ((unsigned int*)tmp)[0]; vv.y = ((unsigned int*)tmp)[1];
      vv.z = ((unsigned int*)tmp)[2]; vv.w = ((unsigned int*)tmp)[3];
      __builtin_nontemporal_store(vv,
          (u32x4v*)(xsT + (size_t)(d0 + c) * L_SEQ + l0 + seg * 8));
    }
    __syncthreads();
  }
}

extern "C" void kernel_launch(void* const* d_in, const int* in_sizes, int n_in,
                              void* d_out, int out_size, void* d_ws, size_t ws_size,
                              hipStream_t stream) {
  const float* x       = (const float*)d_in[0];
  const float* W_in    = (const float*)d_in[1];
  const float* conv_w  = (const float*)d_in[2];
  const float* conv_b  = (const float*)d_in[3];
  const float* W_xproj = (const float*)d_in[4];
  const float* dt_w    = (const float*)d_in[5];
  const float* dt_b    = (const float*)d_in[6];
  const float* A_log   = (const float*)d_in[7];
  const float* Dvec    = (const float*)d_in[8];
  const float* W_out   = (const float*)d_in[9];
  float* out = (float*)d_out;

  char* ws = (char*)d_ws;
  const size_t MB = 1024 * 1024;
  bf16* xz    = (bf16*)(ws);             // [2048][2048]
  bf16* buf1  = (bf16*)(ws + 8 * MB);    // [2048][1024] xs, later gated ys
  bf16* WinT  = (bf16*)(ws + 12 * MB);   // [2048][512] (dead after gemm1)
  bf16* xsT   = (bf16*)(ws + 12 * MB);   // [1024][2048] overlays WinT
  bf16* WoutT = (bf16*)(ws + 12 * MB);   // [512][1024] overlays dead xsT (late)
  float* xpcT = (float*)(ws + 16 * MB);  // [33][2048]

  // 1) WinT = W_in^T bf16
  transpose_cast_kernel<<<dim3(2 * DI / 32, DM / 32), 256, 0, stream>>>(
      W_in, WinT, DM, 2 * DI);
  // 2) xz = x @ W_in  (full N=2048; A fp32 cast-on-stage)
  gemm_bt64<float, bf16><<<dim3(2 * DI / 64, L_SEQ / 64), 256, 0, stream>>>(
      x, WinT, xz, L_SEQ, 2 * DI, DM, DM, 2 * DI);
  // 3) conv + silu -> buf1[l][d] AND xsT[d][l]  (WinT dead)
  conv_silu_dual<<<dim3(DI / 64, L_SEQ / 64), 256, 0, stream>>>(
      xz, conv_w, conv_b, buf1, xsT);
  // 4) xpcT = (xs @ W_xproj)^T
  gemm_xproj<<<dim3(1, L_SEQ / 64), 256, 0, stream>>>(buf1, W_xproj, xpcT);
  // 5) scan: un-gated yT in place over xsT
  scan_kernel<<<DI / 4, 1024, 0, stream>>>(xsT, xpcT, dt_w, dt_b, A_log, Dvec);
  // 6) gate + transpose: ys[l][d] = yT * silu(z), z = xz cols 1024.. (ld 2048)
  gate_transpose_kernel<<<dim3(L_SEQ / 64, DI / 64), 256, 0, stream>>>(
      xsT, xz + DI, 2 * DI, buf1);
  // 7) WoutT = W_out^T bf16 (xsT dead now)
  transpose_cast_kernel<<<dim3(DM / 32, DI / 32), 256, 0, stream>>>(
      W_out, WoutT, DI, DM);
  // 8) out = ys @ W_out
  gemm_bt64<bf16, float><<<dim3(DM / 64, L_SEQ / 64), 256, 0, stream>>>(
      buf1, WoutT, out, L_SEQ, DM, DI, DI, DM);
}